// Round 11
// baseline (1694.635 us; speedup 1.0000x reference)
//
#include <hip/hip_runtime.h>
#include <hip/hip_bf16.h>
#include <string.h>

#define NN 100000
#define TT 64
#define EE 1000000
#define LOG2E 1.44269504088896340736f

typedef __attribute__((ext_vector_type(8))) short bf16x8;
typedef __attribute__((ext_vector_type(4))) float f32x4;
typedef unsigned int u32;
typedef unsigned short u16;

__device__ __forceinline__ float bflo(u32 u) { return __builtin_bit_cast(float, u << 16); }
__device__ __forceinline__ float bfhi(u32 u) { return __builtin_bit_cast(float, u & 0xffff0000u); }
__device__ __forceinline__ u16 f2bf(float f) {
    u32 u = __builtin_bit_cast(u32, f);
    return (u16)((u + 0x7fffu + ((u >> 16) & 1u)) >> 16);
}
__device__ __forceinline__ u32 pack2(float a, float b) {
    return (u32)f2bf(a) | ((u32)f2bf(b) << 16);
}
// v_cvt_pk_bf16_f32 path (gfx950); memcpy avoids non-trivially-copyable bit_cast
__device__ __forceinline__ u32 pack2c(float a, float b) {
    __hip_bfloat162 t = __float22bfloat162_rn(make_float2(a, b));
    u32 r;
    __builtin_memcpy(&r, &t, 4);
    return r;
}
// raw v_exp_f32 — avoids OCML's guarded __ocml_exp2_f32 (harness compiles w/o -ffast-math)
__device__ __forceinline__ float ex2(float x) { return __builtin_amdgcn_exp2f(x); }
__device__ __forceinline__ float fast_rcp(float x) { return __builtin_amdgcn_rcpf(x); }
__device__ __forceinline__ float tanhf_fast(float v) {
    return fmaf(2.f, fast_rcp(1.f + ex2(-2.f * LOG2E * v)), -1.f);
}
#define MFMA16(A, B, C) __builtin_amdgcn_mfma_f32_16x16x32_bf16((A), (B), (C), 0, 0, 0)

// ---------------------------------------------------------------------------
// LSTM: 16 nodes/wave, MFMA 16x16x32 bf16, swapped operands:
//   A = pre-scaled weights (wfrag LDS), B = h (2 ds_read_b128/step, shared),
//   D[gate = t*16 + q*4 + r][node = cl] at lane (q,cl).
// K=96: tail A = compact wtail[256]+zero block; tail B = (x0,x1,1,0..).
// sc=LOG2E (i,f,o) / 2*LOG2E (g) pre-folded -> bare v_exp_f32 activations.
//
// LAUNCH-BOUNDS LAW (this toolchain): waves-per-eu = [arg,arg] — arg is BOTH
// the VGPR cap (256/arg) and the occupancy cap. (256,2) pinned us at
// 2 waves/SIMD / 19%. Round-11 experiment: (256,3) -> 84-reg cap; the raw-exp2
// body's live set (~75 regs) should now fit (rounds 5/6 spilled here only
// because OCML exp2f inflated pressure). Diagnostic: FETCH ~25 MB = fit;
// FETCH >500 MB = spill, revert.  Step-loop unroll 1 to halve transient ranges.
// ---------------------------------------------------------------------------
__global__ __launch_bounds__(256, 3) void lstm_kernel(
    const float* __restrict__ x,     // [NN*TT*2]
    const float* __restrict__ w_ih,  // [256*2]
    const float* __restrict__ w_hh,  // [256*64]
    const float* __restrict__ b_ih,  // [256]
    const float* __restrict__ b_hh,  // [256]
    u16* __restrict__ h_out)         // [NN*64] bf16 (internal format)
{
    __shared__ __align__(16) u16 wfrag[32 * 64 * 8];   // 32 KB   A-fragments k<64
    __shared__ __align__(8) uint2 wtail[272];          // 2.1 KB  compact tail + zeros
    __shared__ __align__(8) u32 x_lds[4][162];         // 2.6 KB  packed bf16 x chunk
    __shared__ __align__(16) u16 h_buf[4][16 * 72];    // 9.2 KB  per-wave h, pad 72

    const int tid = threadIdx.x;
    const int wv = tid >> 6, lane = tid & 63;
    const int q = lane >> 4, cl = lane & 15;
    const int node_base = (blockIdx.x * 4 + wv) * 16;

    // stage A = w_hh fragments, pre-scaled per gate tile
    for (int f = wv; f < 32; f += 4) {
        int t = f >> 1, kh = f & 1;
        float sc = (t >= 8 && t < 12) ? (2.f * LOG2E) : LOG2E;
        int n = t * 16 + cl;
        int k = kh * 32 + q * 8;
        const float4* s4 = (const float4*)(w_hh + n * 64 + k);
        float4 u0 = s4[0], u1 = s4[1];
        u16* d = wfrag + (f * 64 + lane) * 8;
        d[0] = f2bf(u0.x * sc); d[1] = f2bf(u0.y * sc);
        d[2] = f2bf(u0.z * sc); d[3] = f2bf(u0.w * sc);
        d[4] = f2bf(u1.x * sc); d[5] = f2bf(u1.y * sc);
        d[6] = f2bf(u1.z * sc); d[7] = f2bf(u1.w * sc);
    }
    // compact wtail: entry t*16+c = (wih0*sc, wih1*sc, bias*sc, 0); 256..271 = 0
    {
        int t = tid >> 4, c = tid & 15;
        float sc = (t >= 8 && t < 12) ? (2.f * LOG2E) : LOG2E;
        int g = t * 16 + c;
        wtail[tid] = make_uint2(pack2(w_ih[g * 2 + 0] * sc, w_ih[g * 2 + 1] * sc),
                                (u32)f2bf((b_ih[g] + b_hh[g]) * sc));
    }
    if (tid < 16) wtail[256 + tid] = make_uint2(0u, 0u);
    // zero h (step 0 runs the uniform 3-MFMA path)
    {
        u32* hz = (u32*)h_buf[wv];
        for (int i = lane; i < 576; i += 64) hz[i] = 0u;
    }
    // x chunk plan: chunk = 8 steps; per wave 64 float4 = 1/lane.
    const int nl = lane >> 2, f4 = lane & 3;
    int gnd = node_base + nl; gnd = gnd < NN ? gnd : NN - 1;
    const float* px = x + ((size_t)gnd * 64 + f4 * 2) * 2;
    float4 xr = *(const float4*)px;   // chunk 0 in flight
    __syncthreads();  // wfrag/wtail ready

    u16* hb = h_buf[wv];
    u32* xl = x_lds[wv];
    const bool q0 = (q == 0);
    const int wt_base = q0 ? cl : 256;
    const int wt_str = q0 ? 16 : 1;
    const f32x4 zero4 = {0.f, 0.f, 0.f, 0.f};
    float cst[16];
#pragma unroll
    for (int i = 0; i < 16; ++i) cst[i] = 0.f;

    for (int c = 0; c < 8; ++c) {
        // commit chunk c to per-wave LDS (same-wave DS is in-order)
        *((uint2*)(xl + nl * 10 + f4 * 2)) =
            make_uint2(pack2c(xr.x, xr.y), pack2c(xr.z, xr.w));
        if (c < 7) xr = *(const float4*)(px + (c + 1) * 16);
#pragma unroll 1
        for (int s = 0; s < 8; ++s) {
            // B = h: lane (q,cl) holds B[k=q*8+j][n=cl] = h[node=cl][unit=q*8+j]
            bf16x8 bh0 = *(const bf16x8*)(hb + cl * 72 + q * 8);
            bf16x8 bh1 = *(const bf16x8*)(hb + cl * 72 + 32 + q * 8);
            // tail B = (x0,x1,1,0,...) for node cl — tail A zero for q!=0
            uint4 xt;
            xt.x = xl[cl * 10 + s];
            xt.y = 0x00003F80u;   // bf16(1.0) in slot j=2
            xt.z = 0u; xt.w = 0u;
            bf16x8 bx = __builtin_bit_cast(bf16x8, xt);
#pragma unroll
            for (int tg = 0; tg < 4; ++tg) {
                f32x4 accI, accF, accG, accO;
                {
                    const int t = tg;
                    bf16x8 a0 = *(const bf16x8*)(wfrag + ((t * 2 + 0) * 64 + lane) * 8);
                    bf16x8 a1 = *(const bf16x8*)(wfrag + ((t * 2 + 1) * 64 + lane) * 8);
                    uint2 wt = wtail[wt_base + t * wt_str];
                    uint4 wx; wx.x = wt.x; wx.y = wt.y; wx.z = 0u; wx.w = 0u;
                    accI = MFMA16(a0, bh0, zero4);
                    accI = MFMA16(a1, bh1, accI);
                    accI = MFMA16(__builtin_bit_cast(bf16x8, wx), bx, accI);
                }
                {
                    const int t = tg + 4;
                    bf16x8 a0 = *(const bf16x8*)(wfrag + ((t * 2 + 0) * 64 + lane) * 8);
                    bf16x8 a1 = *(const bf16x8*)(wfrag + ((t * 2 + 1) * 64 + lane) * 8);
                    uint2 wt = wtail[wt_base + t * wt_str];
                    uint4 wx; wx.x = wt.x; wx.y = wt.y; wx.z = 0u; wx.w = 0u;
                    accF = MFMA16(a0, bh0, zero4);
                    accF = MFMA16(a1, bh1, accF);
                    accF = MFMA16(__builtin_bit_cast(bf16x8, wx), bx, accF);
                }
                {
                    const int t = tg + 8;
                    bf16x8 a0 = *(const bf16x8*)(wfrag + ((t * 2 + 0) * 64 + lane) * 8);
                    bf16x8 a1 = *(const bf16x8*)(wfrag + ((t * 2 + 1) * 64 + lane) * 8);
                    uint2 wt = wtail[wt_base + t * wt_str];
                    uint4 wx; wx.x = wt.x; wx.y = wt.y; wx.z = 0u; wx.w = 0u;
                    accG = MFMA16(a0, bh0, zero4);
                    accG = MFMA16(a1, bh1, accG);
                    accG = MFMA16(__builtin_bit_cast(bf16x8, wx), bx, accG);
                }
                {
                    const int t = tg + 12;
                    bf16x8 a0 = *(const bf16x8*)(wfrag + ((t * 2 + 0) * 64 + lane) * 8);
                    bf16x8 a1 = *(const bf16x8*)(wfrag + ((t * 2 + 1) * 64 + lane) * 8);
                    uint2 wt = wtail[wt_base + t * wt_str];
                    uint4 wx; wx.x = wt.x; wx.y = wt.y; wx.z = 0u; wx.w = 0u;
                    accO = MFMA16(a0, bh0, zero4);
                    accO = MFMA16(a1, bh1, accO);
                    accO = MFMA16(__builtin_bit_cast(bf16x8, wx), bx, accO);
                }
                // elementwise: node = cl, unit u = tg*16 + q*4 + r (pre-scaled accs)
                float h0, h1, h2, h3;
                {
                    float ig = fast_rcp(1.f + ex2(-accI[0]));
                    float fg = fast_rcp(1.f + ex2(-accF[0]));
                    float gg = fmaf(2.f, fast_rcp(1.f + ex2(-accG[0])), -1.f);
                    float og = fast_rcp(1.f + ex2(-accO[0]));
                    float cc = fmaf(fg, cst[tg * 4 + 0], ig * gg);
                    cst[tg * 4 + 0] = cc;
                    h0 = og * tanhf_fast(cc);
                }
                {
                    float ig = fast_rcp(1.f + ex2(-accI[1]));
                    float fg = fast_rcp(1.f + ex2(-accF[1]));
                    float gg = fmaf(2.f, fast_rcp(1.f + ex2(-accG[1])), -1.f);
                    float og = fast_rcp(1.f + ex2(-accO[1]));
                    float cc = fmaf(fg, cst[tg * 4 + 1], ig * gg);
                    cst[tg * 4 + 1] = cc;
                    h1 = og * tanhf_fast(cc);
                }
                {
                    float ig = fast_rcp(1.f + ex2(-accI[2]));
                    float fg = fast_rcp(1.f + ex2(-accF[2]));
                    float gg = fmaf(2.f, fast_rcp(1.f + ex2(-accG[2])), -1.f);
                    float og = fast_rcp(1.f + ex2(-accO[2]));
                    float cc = fmaf(fg, cst[tg * 4 + 2], ig * gg);
                    cst[tg * 4 + 2] = cc;
                    h2 = og * tanhf_fast(cc);
                }
                {
                    float ig = fast_rcp(1.f + ex2(-accI[3]));
                    float fg = fast_rcp(1.f + ex2(-accF[3]));
                    float gg = fmaf(2.f, fast_rcp(1.f + ex2(-accG[3])), -1.f);
                    float og = fast_rcp(1.f + ex2(-accO[3]));
                    float cc = fmaf(fg, cst[tg * 4 + 3], ig * gg);
                    cst[tg * 4 + 3] = cc;
                    h3 = og * tanhf_fast(cc);
                }
                // write h[node=cl][units tg*16+4q .. +3] — one ds_write_b64
                *((uint2*)(hb + cl * 72 + tg * 16 + q * 4)) =
                    make_uint2(pack2c(h0, h1), pack2c(h2, h3));
            }
        }
    }
    // write h to global (coalesced u32 pairs) — layout [node][unit]
#pragma unroll
    for (int i = 0; i < 8; ++i) {
        int id = i * 64 + lane;
        int row = id >> 5, col2 = (id & 31) * 2;
        int nd = node_base + row;
        if (nd < NN) {
            u32 u = *(const u32*)(hb + row * 72 + col2);
            *((u32*)(h_out + (size_t)nd * 64 + col2)) = u;
        }
    }
}

// ---------------------------------------------------------------------------
// watt[v][k] = sum_d att_v[d] * gat_w[head_v*64+d][k]   (v: 0=src h0, 1=src h1,
// 2=dst h0, 3=dst h1).  Folds attention dots into the xh GEMM as extra rows.
// ---------------------------------------------------------------------------
__global__ void watt_kernel(const float* __restrict__ gat_w,
                            const float* __restrict__ att_src,
                            const float* __restrict__ att_dst,
                            float* __restrict__ watt) {  // [4*64]
    int tid = threadIdx.x;
    int v = tid >> 6, k = tid & 63;
    int head = v & 1;
    const float* att = (v < 2) ? att_src : att_dst;
    float acc = 0.f;
#pragma unroll 8
    for (int d = 0; d < 64; ++d)
        acc = fmaf(att[head * 64 + d], gat_w[(head * 64 + d) * 64 + k], acc);
    watt[v * 64 + k] = acc;
}

// ---------------------------------------------------------------------------
// xh via MFMA: one wave per 16 nodes. A = gat_w tiles (LDS), B = h (global).
// D[col = t*16+q*4+r][node = cl]; tiles t/t+4 = head0/head1 at same lane.
// watt tile: q==0 lanes hold (asrc0, asrc1, adst0, adst1) for node cl.
// ---------------------------------------------------------------------------
__global__ __launch_bounds__(256, 2) void xh_kernel(
    const u16* __restrict__ h,        // [NN*64] bf16 (internal)
    const float* __restrict__ gat_w,  // [128*64] f32
    const float* __restrict__ watt,   // [4*64] f32
    u32* __restrict__ xh,             // [NN*64] packed bf16 pairs
    float2* __restrict__ asrc,
    float2* __restrict__ adst)
{
    __shared__ __align__(16) u16 afrag[16 * 64 * 8];   // 16 KB
    const int tid = threadIdx.x;
    const int wv = tid >> 6, lane = tid & 63;
    const int q = lane >> 4, cl = lane & 15;

    // stage A = gat_w fragments (tile t: rows t*16..+15 = output cols)
    for (int f = wv; f < 16; f += 4) {
        int t = f >> 1, kh = f & 1;
        const float4* s4 = (const float4*)(gat_w + (t * 16 + cl) * 64 + kh * 32 + q * 8);
        float4 u0 = s4[0], u1 = s4[1];
        u16* d = afrag + (f * 64 + lane) * 8;
        d[0] = f2bf(u0.x); d[1] = f2bf(u0.y); d[2] = f2bf(u0.z); d[3] = f2bf(u0.w);
        d[4] = f2bf(u1.x); d[5] = f2bf(u1.y); d[6] = f2bf(u1.z); d[7] = f2bf(u1.w);
    }
    // watt A-fragments in registers (rows cl<4 = att vectors, else 0)
    uint4 wa0u = make_uint4(0u, 0u, 0u, 0u), wa1u = wa0u;
    if (cl < 4) {
        const float* wp = watt + cl * 64;
        float4 a = *(const float4*)(wp + q * 8), b = *(const float4*)(wp + q * 8 + 4);
        wa0u = make_uint4(pack2(a.x, a.y), pack2(a.z, a.w), pack2(b.x, b.y), pack2(b.z, b.w));
        a = *(const float4*)(wp + 32 + q * 8); b = *(const float4*)(wp + 32 + q * 8 + 4);
        wa1u = make_uint4(pack2(a.x, a.y), pack2(a.z, a.w), pack2(b.x, b.y), pack2(b.z, b.w));
    }
    // B = h for node cl
    int node = blockIdx.x * 64 + wv * 16 + cl;
    node = node < NN ? node : NN - 1;   // clamped lanes duplicate NN-1 (same values)
    const u16* hp = h + (size_t)node * 64;
    bf16x8 bh0 = *(const bf16x8*)(hp + q * 8);
    bf16x8 bh1 = *(const bf16x8*)(hp + 32 + q * 8);
    __syncthreads();

    const f32x4 zero4 = {0.f, 0.f, 0.f, 0.f};
    f32x4 acc[8];
#pragma unroll
    for (int t = 0; t < 8; ++t) {
        bf16x8 a0 = *(const bf16x8*)(afrag + ((t * 2 + 0) * 64 + lane) * 8);
        bf16x8 a1 = *(const bf16x8*)(afrag + ((t * 2 + 1) * 64 + lane) * 8);
        acc[t] = MFMA16(a0, bh0, zero4);
        acc[t] = MFMA16(a1, bh1, acc[t]);
    }
    f32x4 aw = MFMA16(__builtin_bit_cast(bf16x8, wa0u), bh0, zero4);
    aw = MFMA16(__builtin_bit_cast(bf16x8, wa1u), bh1, aw);

    // stores: xh[node][c] = pack(head0 c, head1 c), c = t*16+q*4+r
#pragma unroll
    for (int t = 0; t < 4; ++t) {
        uint4 o;
        o.x = pack2c(acc[t][0], acc[t + 4][0]);
        o.y = pack2c(acc[t][1], acc[t + 4][1]);
        o.z = pack2c(acc[t][2], acc[t + 4][2]);
        o.w = pack2c(acc[t][3], acc[t + 4][3]);
        *((uint4*)(xh + (size_t)node * 64 + t * 16 + q * 4)) = o;
    }
    if (q == 0) {
        asrc[node] = make_float2(aw[0], aw[1]);
        adst[node] = make_float2(aw[2], aw[3]);
    }
}

// ------------------------- CSR build -------------------------
__global__ void hist_kernel(const int* __restrict__ ei, u32* __restrict__ deg) {
    int e = blockIdx.x * 256 + threadIdx.x;
    if (e < EE) atomicAdd(&deg[ei[EE + e]], 1u);
}

__global__ void scan1_kernel(u32* rp, u32* bsum) {
    __shared__ u32 tmp[256];
    int i = blockIdx.x * 256 + threadIdx.x;
    u32 v = (i < NN) ? rp[i] : 0u;
    tmp[threadIdx.x] = v;
    __syncthreads();
    for (int off = 1; off < 256; off <<= 1) {
        u32 t = (threadIdx.x >= (u32)off) ? tmp[threadIdx.x - off] : 0u;
        __syncthreads();
        tmp[threadIdx.x] += t;
        __syncthreads();
    }
    if (i < NN) rp[i] = tmp[threadIdx.x] - v;
    if (threadIdx.x == 255) bsum[blockIdx.x] = tmp[255];
}

__global__ void scan2_kernel(u32* bsum) {
    __shared__ u32 tmp[512];
    int tid = threadIdx.x;
    u32 v = (tid < 391) ? bsum[tid] : 0u;
    tmp[tid] = v;
    __syncthreads();
    for (int off = 1; off < 512; off <<= 1) {
        u32 t = (tid >= off) ? tmp[tid - off] : 0u;
        __syncthreads();
        tmp[tid] += t;
        __syncthreads();
    }
    if (tid < 391) bsum[tid] = tmp[tid] - v;
}

__global__ void scan3_kernel(u32* rp, const u32* __restrict__ bsum, u32* __restrict__ cursor) {
    int i = blockIdx.x * 256 + threadIdx.x;
    if (i < NN) {
        u32 v = rp[i] + bsum[blockIdx.x];
        rp[i] = v;
        cursor[i] = v;
    }
    if (blockIdx.x == 0 && threadIdx.x == 0) rp[NN] = EE;
}

__global__ void fill_kernel(const int* __restrict__ ei, u32* __restrict__ cursor,
                            int* __restrict__ csr) {
    int e = blockIdx.x * 256 + threadIdx.x;
    if (e < EE) {
        int s = ei[e], d = ei[EE + e];
        u32 p = atomicAdd(&cursor[d], 1u);
        csr[p] = s;
    }
}

// ---------------------------------------------------------------------------
// Gather: wave per node, lane = channel; z factors out; unroll-by-2 keeps two
// edges' dependent loads in flight. Fused bias+relu+linear+sigmoid epilogue.
// ---------------------------------------------------------------------------
__global__ __launch_bounds__(256) void gather_kernel(
    const u32* __restrict__ xh,
    const float2* __restrict__ asrc,
    const float2* __restrict__ adst,
    const u32* __restrict__ rp,
    const int* __restrict__ csr,
    const float* __restrict__ gat_b,  // [64]
    const float* __restrict__ lin_w,  // [2*64]
    const float* __restrict__ lin_b,  // [2]
    float2* __restrict__ out)         // [NN] (y0,y1) f32
{
    int wv = threadIdx.x >> 6, lane = threadIdx.x & 63;
    int node = blockIdx.x * 4 + wv;
    float2 ad = adst[node];
    float2 as = asrc[node];
    // self-loop
    float e0 = as.x + ad.x; e0 = e0 > 0.f ? e0 : 0.2f * e0;
    float e1 = as.y + ad.y; e1 = e1 > 0.f ? e1 : 0.2f * e1;
    float w0 = ex2(LOG2E * e0);
    float w1 = ex2(LOG2E * e1);
    u32 u = xh[(size_t)node * 64 + lane];
    float acc0 = w0 * bflo(u), acc1 = w1 * bfhi(u);
    float z0 = w0, z1 = w1;
    u32 beg = rp[node], end = rp[node + 1];
    u32 p = beg;
    for (; p + 2 <= end; p += 2) {
        int s0 = csr[p], s1 = csr[p + 1];
        float2 A0 = asrc[s0], A1 = asrc[s1];
        u32 u0 = xh[(size_t)s0 * 64 + lane];
        u32 u1 = xh[(size_t)s1 * 64 + lane];
        float f00 = A0.x + ad.x; f00 = f00 > 0.f ? f00 : 0.2f * f00;
        float f01 = A0.y + ad.y; f01 = f01 > 0.f ? f01 : 0.2f * f01;
        float f10 = A1.x + ad.x; f10 = f10 > 0.f ? f10 : 0.2f * f10;
        float f11 = A1.y + ad.y; f11 = f11 > 0.f ? f11 : 0.2f * f11;
        float v00 = ex2(LOG2E * f00);
        float v01 = ex2(LOG2E * f01);
        float v10 = ex2(LOG2E * f10);
        float v11 = ex2(LOG2E * f11);
        acc0 = fmaf(v00, bflo(u0), acc0);
        acc1 = fmaf(v01, bfhi(u0), acc1);
        acc0 = fmaf(v10, bflo(u1), acc0);
        acc1 = fmaf(v11, bfhi(u1), acc1);
        z0 += v00 + v10;
        z1 += v01 + v11;
    }
    if (p < end) {
        int s = csr[p];
        float2 a2 = asrc[s];
        u32 uu = xh[(size_t)s * 64 + lane];
        float f0 = a2.x + ad.x; f0 = f0 > 0.f ? f0 : 0.2f * f0;
        float f1 = a2.y + ad.y; f1 = f1 > 0.f ? f1 : 0.2f * f1;
        float v0 = ex2(LOG2E * f0);
        float v1 = ex2(LOG2E * f1);
        acc0 = fmaf(v0, bflo(uu), acc0);
        acc1 = fmaf(v1, bfhi(uu), acc1);
        z0 += v0;
        z1 += v1;
    }
    float od = 0.5f * (acc0 * fast_rcp(z0) + acc1 * fast_rcp(z1)) + gat_b[lane];
    od = fmaxf(od, 0.f);
    float p0 = od * lin_w[lane];
    float p1 = od * lin_w[64 + lane];
#pragma unroll
    for (int off = 32; off > 0; off >>= 1) {
        p0 += __shfl_xor(p0, off);
        p1 += __shfl_xor(p1, off);
    }
    if (lane == 0) {
        float y0 = fast_rcp(1.f + ex2(-LOG2E * (p0 + lin_b[0])));
        float y1 = fast_rcp(1.f + ex2(-LOG2E * (p1 + lin_b[1])));
        out[node] = make_float2(y0, y1);
    }
}

extern "C" void kernel_launch(void* const* d_in, const int* in_sizes, int n_in,
                              void* d_out, int out_size, void* d_ws, size_t ws_size,
                              hipStream_t stream) {
    const float* x = (const float*)d_in[0];
    const int* ei = (const int*)d_in[1];
    const float* w_ih = (const float*)d_in[2];
    const float* w_hh = (const float*)d_in[3];
    const float* b_ih = (const float*)d_in[4];
    const float* b_hh = (const float*)d_in[5];
    const float* gat_w = (const float*)d_in[6];
    const float* att_src = (const float*)d_in[7];
    const float* att_dst = (const float*)d_in[8];
    const float* gat_b = (const float*)d_in[9];
    const float* lin_w = (const float*)d_in[10];
    const float* lin_b = (const float*)d_in[11];

    char* w = (char*)d_ws;
    u16* h = (u16*)(w);                           // 12,800,000 B
    u32* xh = (u32*)(w + 12800000);               // 25,600,000 B
    float2* asrc = (float2*)(w + 38400000);       //    800,000 B
    float2* adst = (float2*)(w + 39200000);       //    800,000 B
    u32* rp = (u32*)(w + 40000000);               //    400,128 B (deg -> row_ptr)
    u32* cursor = (u32*)(w + 40400128);           //    400,000 B
    u32* bsum = (u32*)(w + 40800128);             //      2,048 B
    int* csr = (int*)(w + 40802176);              //  4,000,000 B
    float* watt = (float*)(w + 44802176);         //      1,024 B

    (void)hipMemsetAsync(rp, 0, (NN + 1) * sizeof(u32), stream);
    lstm_kernel<<<1563, 256, 0, stream>>>(x, w_ih, w_hh, b_ih, b_hh, h);
    watt_kernel<<<1, 256, 0, stream>>>(gat_w, att_src, att_dst, watt);
    xh_kernel<<<1563, 256, 0, stream>>>(h, gat_w, watt, xh, asrc, adst);
    hist_kernel<<<(EE + 255) / 256, 256, 0, stream>>>(ei, rp);
    scan1_kernel<<<391, 256, 0, stream>>>(rp, bsum);
    scan2_kernel<<<1, 512, 0, stream>>>(bsum);
    scan3_kernel<<<391, 256, 0, stream>>>(rp, bsum, cursor);
    fill_kernel<<<(EE + 255) / 256, 256, 0, stream>>>(ei, cursor, csr);
    gather_kernel<<<NN / 4, 256, 0, stream>>>(xh, asrc, adst, rp, csr, gat_b, lin_w, lin_b,
                                              (float2*)d_out);
}

// Round 12
// 815.668 us; speedup vs baseline: 2.0776x; 2.0776x over previous
//
#include <hip/hip_runtime.h>
#include <hip/hip_bf16.h>
#include <string.h>

#define NN 100000
#define TT 64
#define EE 1000000
#define LOG2E 1.44269504088896340736f

typedef __attribute__((ext_vector_type(8))) short bf16x8;
typedef __attribute__((ext_vector_type(4))) float f32x4;
typedef unsigned int u32;
typedef unsigned short u16;

__device__ __forceinline__ float bflo(u32 u) { return __builtin_bit_cast(float, u << 16); }
__device__ __forceinline__ float bfhi(u32 u) { return __builtin_bit_cast(float, u & 0xffff0000u); }
__device__ __forceinline__ u16 f2bf(float f) {
    u32 u = __builtin_bit_cast(u32, f);
    return (u16)((u + 0x7fffu + ((u >> 16) & 1u)) >> 16);
}
__device__ __forceinline__ u32 pack2(float a, float b) {
    return (u32)f2bf(a) | ((u32)f2bf(b) << 16);
}
// v_cvt_pk_bf16_f32 path (gfx950); memcpy avoids non-trivially-copyable bit_cast
__device__ __forceinline__ u32 pack2c(float a, float b) {
    __hip_bfloat162 t = __float22bfloat162_rn(make_float2(a, b));
    u32 r;
    __builtin_memcpy(&r, &t, 4);
    return r;
}
// raw v_exp_f32 — avoids OCML's guarded __ocml_exp2_f32 (harness compiles w/o -ffast-math)
__device__ __forceinline__ float ex2(float x) { return __builtin_amdgcn_exp2f(x); }
__device__ __forceinline__ float fast_rcp(float x) { return __builtin_amdgcn_rcpf(x); }
__device__ __forceinline__ float tanhf_fast(float v) {
    return fmaf(2.f, fast_rcp(1.f + ex2(-2.f * LOG2E * v)), -1.f);
}
#define MFMA16(A, B, C) __builtin_amdgcn_mfma_f32_16x16x32_bf16((A), (B), (C), 0, 0, 0)

// ---------------------------------------------------------------------------
// LSTM: 16 nodes/wave, MFMA 16x16x32 bf16, swapped operands:
//   A = pre-scaled weights (wfrag LDS), B = h (2 ds_read_b128/step, shared),
//   D[gate = t*16 + q*4 + r][node = cl] at lane (q,cl).
// K=96: tail A = compact wtail[256]+zero block; tail B = (x0,x1,1,0..).
// sc=LOG2E (i,f,o) / 2*LOG2E (g) pre-folded -> bare v_exp_f32 activations.
//
// LAUNCH-BOUNDS LAWS (confirmed rounds 4-11 on this toolchain):
//   * VGPR cap = 256/min_waves.  84 regs (min=3) SPILLS this body (r11:
//     4.3 GB FETCH); 128 regs (min=2) fits (r10: 25 MB FETCH).
//   * The 2nd launch_bounds arg is ALSO the occupancy cap ([min,max]=[a,a]):
//     r10 pinned at 2 waves/EU (19%) though LDS/VGPR permit 3.
// Round-12: amdgpu_waves_per_eu(2,4) = 128-reg budget + lifted residency cap.
// ---------------------------------------------------------------------------
__global__ __launch_bounds__(256)
__attribute__((amdgpu_waves_per_eu(2, 4))) void lstm_kernel(
    const float* __restrict__ x,     // [NN*TT*2]
    const float* __restrict__ w_ih,  // [256*2]
    const float* __restrict__ w_hh,  // [256*64]
    const float* __restrict__ b_ih,  // [256]
    const float* __restrict__ b_hh,  // [256]
    u16* __restrict__ h_out)         // [NN*64] bf16 (internal format)
{
    __shared__ __align__(16) u16 wfrag[32 * 64 * 8];   // 32 KB   A-fragments k<64
    __shared__ __align__(8) uint2 wtail[272];          // 2.1 KB  compact tail + zeros
    __shared__ __align__(8) u32 x_lds[4][162];         // 2.6 KB  packed bf16 x chunk
    __shared__ __align__(16) u16 h_buf[4][16 * 72];    // 9.2 KB  per-wave h, pad 72

    const int tid = threadIdx.x;
    const int wv = tid >> 6, lane = tid & 63;
    const int q = lane >> 4, cl = lane & 15;
    const int node_base = (blockIdx.x * 4 + wv) * 16;

    // stage A = w_hh fragments, pre-scaled per gate tile
    for (int f = wv; f < 32; f += 4) {
        int t = f >> 1, kh = f & 1;
        float sc = (t >= 8 && t < 12) ? (2.f * LOG2E) : LOG2E;
        int n = t * 16 + cl;
        int k = kh * 32 + q * 8;
        const float4* s4 = (const float4*)(w_hh + n * 64 + k);
        float4 u0 = s4[0], u1 = s4[1];
        u16* d = wfrag + (f * 64 + lane) * 8;
        d[0] = f2bf(u0.x * sc); d[1] = f2bf(u0.y * sc);
        d[2] = f2bf(u0.z * sc); d[3] = f2bf(u0.w * sc);
        d[4] = f2bf(u1.x * sc); d[5] = f2bf(u1.y * sc);
        d[6] = f2bf(u1.z * sc); d[7] = f2bf(u1.w * sc);
    }
    // compact wtail: entry t*16+c = (wih0*sc, wih1*sc, bias*sc, 0); 256..271 = 0
    {
        int t = tid >> 4, c = tid & 15;
        float sc = (t >= 8 && t < 12) ? (2.f * LOG2E) : LOG2E;
        int g = t * 16 + c;
        wtail[tid] = make_uint2(pack2(w_ih[g * 2 + 0] * sc, w_ih[g * 2 + 1] * sc),
                                (u32)f2bf((b_ih[g] + b_hh[g]) * sc));
    }
    if (tid < 16) wtail[256 + tid] = make_uint2(0u, 0u);
    // zero h (step 0 runs the uniform 3-MFMA path)
    {
        u32* hz = (u32*)h_buf[wv];
        for (int i = lane; i < 576; i += 64) hz[i] = 0u;
    }
    // x chunk plan: chunk = 8 steps; per wave 64 float4 = 1/lane.
    const int nl = lane >> 2, f4 = lane & 3;
    int gnd = node_base + nl; gnd = gnd < NN ? gnd : NN - 1;
    const float* px = x + ((size_t)gnd * 64 + f4 * 2) * 2;
    float4 xr = *(const float4*)px;   // chunk 0 in flight
    __syncthreads();  // wfrag/wtail ready

    u16* hb = h_buf[wv];
    u32* xl = x_lds[wv];
    const bool q0 = (q == 0);
    const int wt_base = q0 ? cl : 256;
    const int wt_str = q0 ? 16 : 1;
    const f32x4 zero4 = {0.f, 0.f, 0.f, 0.f};
    float cst[16];
#pragma unroll
    for (int i = 0; i < 16; ++i) cst[i] = 0.f;

    for (int c = 0; c < 8; ++c) {
        // commit chunk c to per-wave LDS (same-wave DS is in-order)
        *((uint2*)(xl + nl * 10 + f4 * 2)) =
            make_uint2(pack2c(xr.x, xr.y), pack2c(xr.z, xr.w));
        if (c < 7) xr = *(const float4*)(px + (c + 1) * 16);
#pragma unroll 2
        for (int s = 0; s < 8; ++s) {
            // B = h: lane (q,cl) holds B[k=q*8+j][n=cl] = h[node=cl][unit=q*8+j]
            bf16x8 bh0 = *(const bf16x8*)(hb + cl * 72 + q * 8);
            bf16x8 bh1 = *(const bf16x8*)(hb + cl * 72 + 32 + q * 8);
            // tail B = (x0,x1,1,0,...) for node cl — tail A zero for q!=0
            uint4 xt;
            xt.x = xl[cl * 10 + s];
            xt.y = 0x00003F80u;   // bf16(1.0) in slot j=2
            xt.z = 0u; xt.w = 0u;
            bf16x8 bx = __builtin_bit_cast(bf16x8, xt);
#pragma unroll
            for (int tg = 0; tg < 4; ++tg) {
                f32x4 accI, accF, accG, accO;
                {
                    const int t = tg;
                    bf16x8 a0 = *(const bf16x8*)(wfrag + ((t * 2 + 0) * 64 + lane) * 8);
                    bf16x8 a1 = *(const bf16x8*)(wfrag + ((t * 2 + 1) * 64 + lane) * 8);
                    uint2 wt = wtail[wt_base + t * wt_str];
                    uint4 wx; wx.x = wt.x; wx.y = wt.y; wx.z = 0u; wx.w = 0u;
                    accI = MFMA16(a0, bh0, zero4);
                    accI = MFMA16(a1, bh1, accI);
                    accI = MFMA16(__builtin_bit_cast(bf16x8, wx), bx, accI);
                }
                {
                    const int t = tg + 4;
                    bf16x8 a0 = *(const bf16x8*)(wfrag + ((t * 2 + 0) * 64 + lane) * 8);
                    bf16x8 a1 = *(const bf16x8*)(wfrag + ((t * 2 + 1) * 64 + lane) * 8);
                    uint2 wt = wtail[wt_base + t * wt_str];
                    uint4 wx; wx.x = wt.x; wx.y = wt.y; wx.z = 0u; wx.w = 0u;
                    accF = MFMA16(a0, bh0, zero4);
                    accF = MFMA16(a1, bh1, accF);
                    accF = MFMA16(__builtin_bit_cast(bf16x8, wx), bx, accF);
                }
                {
                    const int t = tg + 8;
                    bf16x8 a0 = *(const bf16x8*)(wfrag + ((t * 2 + 0) * 64 + lane) * 8);
                    bf16x8 a1 = *(const bf16x8*)(wfrag + ((t * 2 + 1) * 64 + lane) * 8);
                    uint2 wt = wtail[wt_base + t * wt_str];
                    uint4 wx; wx.x = wt.x; wx.y = wt.y; wx.z = 0u; wx.w = 0u;
                    accG = MFMA16(a0, bh0, zero4);
                    accG = MFMA16(a1, bh1, accG);
                    accG = MFMA16(__builtin_bit_cast(bf16x8, wx), bx, accG);
                }
                {
                    const int t = tg + 12;
                    bf16x8 a0 = *(const bf16x8*)(wfrag + ((t * 2 + 0) * 64 + lane) * 8);
                    bf16x8 a1 = *(const bf16x8*)(wfrag + ((t * 2 + 1) * 64 + lane) * 8);
                    uint2 wt = wtail[wt_base + t * wt_str];
                    uint4 wx; wx.x = wt.x; wx.y = wt.y; wx.z = 0u; wx.w = 0u;
                    accO = MFMA16(a0, bh0, zero4);
                    accO = MFMA16(a1, bh1, accO);
                    accO = MFMA16(__builtin_bit_cast(bf16x8, wx), bx, accO);
                }
                // elementwise: node = cl, unit u = tg*16 + q*4 + r (pre-scaled accs)
                float h0, h1, h2, h3;
                {
                    float ig = fast_rcp(1.f + ex2(-accI[0]));
                    float fg = fast_rcp(1.f + ex2(-accF[0]));
                    float gg = fmaf(2.f, fast_rcp(1.f + ex2(-accG[0])), -1.f);
                    float og = fast_rcp(1.f + ex2(-accO[0]));
                    float cc = fmaf(fg, cst[tg * 4 + 0], ig * gg);
                    cst[tg * 4 + 0] = cc;
                    h0 = og * tanhf_fast(cc);
                }
                {
                    float ig = fast_rcp(1.f + ex2(-accI[1]));
                    float fg = fast_rcp(1.f + ex2(-accF[1]));
                    float gg = fmaf(2.f, fast_rcp(1.f + ex2(-accG[1])), -1.f);
                    float og = fast_rcp(1.f + ex2(-accO[1]));
                    float cc = fmaf(fg, cst[tg * 4 + 1], ig * gg);
                    cst[tg * 4 + 1] = cc;
                    h1 = og * tanhf_fast(cc);
                }
                {
                    float ig = fast_rcp(1.f + ex2(-accI[2]));
                    float fg = fast_rcp(1.f + ex2(-accF[2]));
                    float gg = fmaf(2.f, fast_rcp(1.f + ex2(-accG[2])), -1.f);
                    float og = fast_rcp(1.f + ex2(-accO[2]));
                    float cc = fmaf(fg, cst[tg * 4 + 2], ig * gg);
                    cst[tg * 4 + 2] = cc;
                    h2 = og * tanhf_fast(cc);
                }
                {
                    float ig = fast_rcp(1.f + ex2(-accI[3]));
                    float fg = fast_rcp(1.f + ex2(-accF[3]));
                    float gg = fmaf(2.f, fast_rcp(1.f + ex2(-accG[3])), -1.f);
                    float og = fast_rcp(1.f + ex2(-accO[3]));
                    float cc = fmaf(fg, cst[tg * 4 + 3], ig * gg);
                    cst[tg * 4 + 3] = cc;
                    h3 = og * tanhf_fast(cc);
                }
                // write h[node=cl][units tg*16+4q .. +3] — one ds_write_b64
                *((uint2*)(hb + cl * 72 + tg * 16 + q * 4)) =
                    make_uint2(pack2c(h0, h1), pack2c(h2, h3));
            }
        }
    }
    // write h to global (coalesced u32 pairs) — layout [node][unit]
#pragma unroll
    for (int i = 0; i < 8; ++i) {
        int id = i * 64 + lane;
        int row = id >> 5, col2 = (id & 31) * 2;
        int nd = node_base + row;
        if (nd < NN) {
            u32 u = *(const u32*)(hb + row * 72 + col2);
            *((u32*)(h_out + (size_t)nd * 64 + col2)) = u;
        }
    }
}

// ---------------------------------------------------------------------------
// watt[v][k] = sum_d att_v[d] * gat_w[head_v*64+d][k]   (v: 0=src h0, 1=src h1,
// 2=dst h0, 3=dst h1).  Folds attention dots into the xh GEMM as extra rows.
// ---------------------------------------------------------------------------
__global__ void watt_kernel(const float* __restrict__ gat_w,
                            const float* __restrict__ att_src,
                            const float* __restrict__ att_dst,
                            float* __restrict__ watt) {  // [4*64]
    int tid = threadIdx.x;
    int v = tid >> 6, k = tid & 63;
    int head = v & 1;
    const float* att = (v < 2) ? att_src : att_dst;
    float acc = 0.f;
#pragma unroll 8
    for (int d = 0; d < 64; ++d)
        acc = fmaf(att[head * 64 + d], gat_w[(head * 64 + d) * 64 + k], acc);
    watt[v * 64 + k] = acc;
}

// ---------------------------------------------------------------------------
// xh via MFMA: one wave per 16 nodes. A = gat_w tiles (LDS), B = h (global).
// D[col = t*16+q*4+r][node = cl]; tiles t/t+4 = head0/head1 at same lane.
// watt tile: q==0 lanes hold (asrc0, asrc1, adst0, adst1) for node cl.
// ---------------------------------------------------------------------------
__global__ __launch_bounds__(256, 2) void xh_kernel(
    const u16* __restrict__ h,        // [NN*64] bf16 (internal)
    const float* __restrict__ gat_w,  // [128*64] f32
    const float* __restrict__ watt,   // [4*64] f32
    u32* __restrict__ xh,             // [NN*64] packed bf16 pairs
    float2* __restrict__ asrc,
    float2* __restrict__ adst)
{
    __shared__ __align__(16) u16 afrag[16 * 64 * 8];   // 16 KB
    const int tid = threadIdx.x;
    const int wv = tid >> 6, lane = tid & 63;
    const int q = lane >> 4, cl = lane & 15;

    // stage A = gat_w fragments (tile t: rows t*16..+15 = output cols)
    for (int f = wv; f < 16; f += 4) {
        int t = f >> 1, kh = f & 1;
        const float4* s4 = (const float4*)(gat_w + (t * 16 + cl) * 64 + kh * 32 + q * 8);
        float4 u0 = s4[0], u1 = s4[1];
        u16* d = afrag + (f * 64 + lane) * 8;
        d[0] = f2bf(u0.x); d[1] = f2bf(u0.y); d[2] = f2bf(u0.z); d[3] = f2bf(u0.w);
        d[4] = f2bf(u1.x); d[5] = f2bf(u1.y); d[6] = f2bf(u1.z); d[7] = f2bf(u1.w);
    }
    // watt A-fragments in registers (rows cl<4 = att vectors, else 0)
    uint4 wa0u = make_uint4(0u, 0u, 0u, 0u), wa1u = wa0u;
    if (cl < 4) {
        const float* wp = watt + cl * 64;
        float4 a = *(const float4*)(wp + q * 8), b = *(const float4*)(wp + q * 8 + 4);
        wa0u = make_uint4(pack2(a.x, a.y), pack2(a.z, a.w), pack2(b.x, b.y), pack2(b.z, b.w));
        a = *(const float4*)(wp + 32 + q * 8); b = *(const float4*)(wp + 32 + q * 8 + 4);
        wa1u = make_uint4(pack2(a.x, a.y), pack2(a.z, a.w), pack2(b.x, b.y), pack2(b.z, b.w));
    }
    // B = h for node cl
    int node = blockIdx.x * 64 + wv * 16 + cl;
    node = node < NN ? node : NN - 1;   // clamped lanes duplicate NN-1 (same values)
    const u16* hp = h + (size_t)node * 64;
    bf16x8 bh0 = *(const bf16x8*)(hp + q * 8);
    bf16x8 bh1 = *(const bf16x8*)(hp + 32 + q * 8);
    __syncthreads();

    const f32x4 zero4 = {0.f, 0.f, 0.f, 0.f};
    f32x4 acc[8];
#pragma unroll
    for (int t = 0; t < 8; ++t) {
        bf16x8 a0 = *(const bf16x8*)(afrag + ((t * 2 + 0) * 64 + lane) * 8);
        bf16x8 a1 = *(const bf16x8*)(afrag + ((t * 2 + 1) * 64 + lane) * 8);
        acc[t] = MFMA16(a0, bh0, zero4);
        acc[t] = MFMA16(a1, bh1, acc[t]);
    }
    f32x4 aw = MFMA16(__builtin_bit_cast(bf16x8, wa0u), bh0, zero4);
    aw = MFMA16(__builtin_bit_cast(bf16x8, wa1u), bh1, aw);

    // stores: xh[node][c] = pack(head0 c, head1 c), c = t*16+q*4+r
#pragma unroll
    for (int t = 0; t < 4; ++t) {
        uint4 o;
        o.x = pack2c(acc[t][0], acc[t + 4][0]);
        o.y = pack2c(acc[t][1], acc[t + 4][1]);
        o.z = pack2c(acc[t][2], acc[t + 4][2]);
        o.w = pack2c(acc[t][3], acc[t + 4][3]);
        *((uint4*)(xh + (size_t)node * 64 + t * 16 + q * 4)) = o;
    }
    if (q == 0) {
        asrc[node] = make_float2(aw[0], aw[1]);
        adst[node] = make_float2(aw[2], aw[3]);
    }
}

// ------------------------- CSR build -------------------------
__global__ void hist_kernel(const int* __restrict__ ei, u32* __restrict__ deg) {
    int e = blockIdx.x * 256 + threadIdx.x;
    if (e < EE) atomicAdd(&deg[ei[EE + e]], 1u);
}

__global__ void scan1_kernel(u32* rp, u32* bsum) {
    __shared__ u32 tmp[256];
    int i = blockIdx.x * 256 + threadIdx.x;
    u32 v = (i < NN) ? rp[i] : 0u;
    tmp[threadIdx.x] = v;
    __syncthreads();
    for (int off = 1; off < 256; off <<= 1) {
        u32 t = (threadIdx.x >= (u32)off) ? tmp[threadIdx.x - off] : 0u;
        __syncthreads();
        tmp[threadIdx.x] += t;
        __syncthreads();
    }
    if (i < NN) rp[i] = tmp[threadIdx.x] - v;
    if (threadIdx.x == 255) bsum[blockIdx.x] = tmp[255];
}

__global__ void scan2_kernel(u32* bsum) {
    __shared__ u32 tmp[512];
    int tid = threadIdx.x;
    u32 v = (tid < 391) ? bsum[tid] : 0u;
    tmp[tid] = v;
    __syncthreads();
    for (int off = 1; off < 512; off <<= 1) {
        u32 t = (tid >= off) ? tmp[tid - off] : 0u;
        __syncthreads();
        tmp[tid] += t;
        __syncthreads();
    }
    if (tid < 391) bsum[tid] = tmp[tid] - v;
}

__global__ void scan3_kernel(u32* rp, const u32* __restrict__ bsum, u32* __restrict__ cursor) {
    int i = blockIdx.x * 256 + threadIdx.x;
    if (i < NN) {
        u32 v = rp[i] + bsum[blockIdx.x];
        rp[i] = v;
        cursor[i] = v;
    }
    if (blockIdx.x == 0 && threadIdx.x == 0) rp[NN] = EE;
}

__global__ void fill_kernel(const int* __restrict__ ei, u32* __restrict__ cursor,
                            int* __restrict__ csr) {
    int e = blockIdx.x * 256 + threadIdx.x;
    if (e < EE) {
        int s = ei[e], d = ei[EE + e];
        u32 p = atomicAdd(&cursor[d], 1u);
        csr[p] = s;
    }
}

// ---------------------------------------------------------------------------
// Gather: wave per node, lane = channel; z factors out; unroll-by-2 keeps two
// edges' dependent loads in flight. Fused bias+relu+linear+sigmoid epilogue.
// ---------------------------------------------------------------------------
__global__ __launch_bounds__(256) void gather_kernel(
    const u32* __restrict__ xh,
    const float2* __restrict__ asrc,
    const float2* __restrict__ adst,
    const u32* __restrict__ rp,
    const int* __restrict__ csr,
    const float* __restrict__ gat_b,  // [64]
    const float* __restrict__ lin_w,  // [2*64]
    const float* __restrict__ lin_b,  // [2]
    float2* __restrict__ out)         // [NN] (y0,y1) f32
{
    int wv = threadIdx.x >> 6, lane = threadIdx.x & 63;
    int node = blockIdx.x * 4 + wv;
    float2 ad = adst[node];
    float2 as = asrc[node];
    // self-loop
    float e0 = as.x + ad.x; e0 = e0 > 0.f ? e0 : 0.2f * e0;
    float e1 = as.y + ad.y; e1 = e1 > 0.f ? e1 : 0.2f * e1;
    float w0 = ex2(LOG2E * e0);
    float w1 = ex2(LOG2E * e1);
    u32 u = xh[(size_t)node * 64 + lane];
    float acc0 = w0 * bflo(u), acc1 = w1 * bfhi(u);
    float z0 = w0, z1 = w1;
    u32 beg = rp[node], end = rp[node + 1];
    u32 p = beg;
    for (; p + 2 <= end; p += 2) {
        int s0 = csr[p], s1 = csr[p + 1];
        float2 A0 = asrc[s0], A1 = asrc[s1];
        u32 u0 = xh[(size_t)s0 * 64 + lane];
        u32 u1 = xh[(size_t)s1 * 64 + lane];
        float f00 = A0.x + ad.x; f00 = f00 > 0.f ? f00 : 0.2f * f00;
        float f01 = A0.y + ad.y; f01 = f01 > 0.f ? f01 : 0.2f * f01;
        float f10 = A1.x + ad.x; f10 = f10 > 0.f ? f10 : 0.2f * f10;
        float f11 = A1.y + ad.y; f11 = f11 > 0.f ? f11 : 0.2f * f11;
        float v00 = ex2(LOG2E * f00);
        float v01 = ex2(LOG2E * f01);
        float v10 = ex2(LOG2E * f10);
        float v11 = ex2(LOG2E * f11);
        acc0 = fmaf(v00, bflo(u0), acc0);
        acc1 = fmaf(v01, bfhi(u0), acc1);
        acc0 = fmaf(v10, bflo(u1), acc0);
        acc1 = fmaf(v11, bfhi(u1), acc1);
        z0 += v00 + v10;
        z1 += v01 + v11;
    }
    if (p < end) {
        int s = csr[p];
        float2 a2 = asrc[s];
        u32 uu = xh[(size_t)s * 64 + lane];
        float f0 = a2.x + ad.x; f0 = f0 > 0.f ? f0 : 0.2f * f0;
        float f1 = a2.y + ad.y; f1 = f1 > 0.f ? f1 : 0.2f * f1;
        float v0 = ex2(LOG2E * f0);
        float v1 = ex2(LOG2E * f1);
        acc0 = fmaf(v0, bflo(uu), acc0);
        acc1 = fmaf(v1, bfhi(uu), acc1);
        z0 += v0;
        z1 += v1;
    }
    float od = 0.5f * (acc0 * fast_rcp(z0) + acc1 * fast_rcp(z1)) + gat_b[lane];
    od = fmaxf(od, 0.f);
    float p0 = od * lin_w[lane];
    float p1 = od * lin_w[64 + lane];
#pragma unroll
    for (int off = 32; off > 0; off >>= 1) {
        p0 += __shfl_xor(p0, off);
        p1 += __shfl_xor(p1, off);
    }
    if (lane == 0) {
        float y0 = fast_rcp(1.f + ex2(-LOG2E * (p0 + lin_b[0])));
        float y1 = fast_rcp(1.f + ex2(-LOG2E * (p1 + lin_b[1])));
        out[node] = make_float2(y0, y1);
    }
}

extern "C" void kernel_launch(void* const* d_in, const int* in_sizes, int n_in,
                              void* d_out, int out_size, void* d_ws, size_t ws_size,
                              hipStream_t stream) {
    const float* x = (const float*)d_in[0];
    const int* ei = (const int*)d_in[1];
    const float* w_ih = (const float*)d_in[2];
    const float* w_hh = (const float*)d_in[3];
    const float* b_ih = (const float*)d_in[4];
    const float* b_hh = (const float*)d_in[5];
    const float* gat_w = (const float*)d_in[6];
    const float* att_src = (const float*)d_in[7];
    const float* att_dst = (const float*)d_in[8];
    const float* gat_b = (const float*)d_in[9];
    const float* lin_w = (const float*)d_in[10];
    const float* lin_b = (const float*)d_in[11];

    char* w = (char*)d_ws;
    u16* h = (u16*)(w);                           // 12,800,000 B
    u32* xh = (u32*)(w + 12800000);               // 25,600,000 B
    float2* asrc = (float2*)(w + 38400000);       //    800,000 B
    float2* adst = (float2*)(w + 39200000);       //    800,000 B
    u32* rp = (u32*)(w + 40000000);               //    400,128 B (deg -> row_ptr)
    u32* cursor = (u32*)(w + 40400128);           //    400,000 B
    u32* bsum = (u32*)(w + 40800128);             //      2,048 B
    int* csr = (int*)(w + 40802176);              //  4,000,000 B
    float* watt = (float*)(w + 44802176);         //      1,024 B

    (void)hipMemsetAsync(rp, 0, (NN + 1) * sizeof(u32), stream);
    lstm_kernel<<<1563, 256, 0, stream>>>(x, w_ih, w_hh, b_ih, b_hh, h);
    watt_kernel<<<1, 256, 0, stream>>>(gat_w, att_src, att_dst, watt);
    xh_kernel<<<1563, 256, 0, stream>>>(h, gat_w, watt, xh, asrc, adst);
    hist_kernel<<<(EE + 255) / 256, 256, 0, stream>>>(ei, rp);
    scan1_kernel<<<391, 256, 0, stream>>>(rp, bsum);
    scan2_kernel<<<1, 512, 0, stream>>>(bsum);
    scan3_kernel<<<391, 256, 0, stream>>>(rp, bsum, cursor);
    fill_kernel<<<(EE + 255) / 256, 256, 0, stream>>>(ei, cursor, csr);
    gather_kernel<<<NN / 4, 256, 0, stream>>>(xh, asrc, adst, rp, csr, gat_b, lin_w, lin_b,
                                              (float2*)d_out);
}